// Round 20
// baseline (517.600 us; speedup 1.0000x reference)
//
#include <hip/hip_runtime.h>
#include <stdint.h>

typedef __attribute__((ext_vector_type(4))) _Float16 half4;
typedef __attribute__((ext_vector_type(2))) _Float16 h2;
typedef __attribute__((ext_vector_type(4))) float f32x4;
typedef __attribute__((ext_vector_type(2))) uint32_t uint2v;
typedef __attribute__((ext_vector_type(2))) short short2v;

#define BLOCK 1024
#define MFMA16 __builtin_amdgcn_mfma_f32_16x16x16f16
#define SCHEDB __builtin_amdgcn_sched_barrier
#define PKRTZ  __builtin_amdgcn_cvt_pkrtz

// LDS byte offsets (total 61632; one 16-wave block per CU = 4 waves/SIMD)
#define TD_OFF    41472     // td A-frags layers I=6..9: 4 x 4608
#define BH_OFF    59904     // bh f32 9*48 = 1728
#define LDS_BYTES 61632

extern __shared__ unsigned char smem[];

#define B32H(X) __builtin_bit_cast(uint32_t, (X))
#define H2U(X)  __builtin_bit_cast(h2, (X))

// RNE pack (scalar casts; off hot path)
#define PACK4(S0,S1,S2,S3) __extension__({ \
  half4 _b; \
  _b[0] = (_Float16)(S0); _b[1] = (_Float16)(S1); \
  _b[2] = (_Float16)(S2); _b[3] = (_Float16)(S3); \
  _b; })
#define PACKU(S0,S1) __extension__({ \
  h2 _x; _x[0] = (_Float16)(S0); _x[1] = (_Float16)(S1); B32H(_x); })

// build half4 MFMA operand from two u32 state words (compile-time indices)
#define VB(ROW, KS) __extension__({ \
  uint2v _u; _u[0] = (ROW)[2*(KS)]; _u[1] = (ROW)[2*(KS)+1]; \
  __builtin_bit_cast(half4, _u); })

// td A-frag selector: layers 1-5 from registers, 6-9 from LDS (I literal)
#define TDA(I, ST) ((I) <= 5 \
  ? tdreg[(I) <= 5 ? (I)-1 : 0][ST] \
  : *(const half4*)(smem + TD_OFF + ((I) >= 6 ? (I)-6 : 0)*4608 + (ST)*512 + lane*8))

// pred 48x48 matvec; B = packed f16 state words directly; bias C-init from bh LDS.
#define PRED48(SRCU, WOFF, LIDX, P0, P1, P2) do { \
  P0 = *(const f32x4*)(smem + BH_OFF + ((LIDX)*48 +  0)*4 + b*16); \
  P1 = *(const f32x4*)(smem + BH_OFF + ((LIDX)*48 + 16)*4 + b*16); \
  P2 = *(const f32x4*)(smem + BH_OFF + ((LIDX)*48 + 32)*4 + b*16); \
  _Pragma("unroll") \
  for (int _ks = 0; _ks < 3; ++_ks) { \
    half4 _B = VB(SRCU, _ks); \
    half4 _A0 = *(const half4*)(smem + (WOFF) + (0*3+_ks)*512 + lane*8); \
    half4 _A1 = *(const half4*)(smem + (WOFF) + (1*3+_ks)*512 + lane*8); \
    half4 _A2 = *(const half4*)(smem + (WOFF) + (2*3+_ks)*512 + lane*8); \
    P0 = MFMA16(_A0, _B, P0, 0, 0, 0); \
    P1 = MFMA16(_A1, _B, P1, 0, 0, 0); \
    P2 = MFMA16(_A2, _B, P2, 0, 0, 0); \
  } \
} while(0)

// td 48x48 matvec; B = packed me words. I literal.
#define TD48(MEU, I, T0, T1, T2) do { \
  T0 = (f32x4){0.f,0.f,0.f,0.f}; T1 = T0; T2 = T0; \
  _Pragma("unroll") \
  for (int _ks = 0; _ks < 3; ++_ks) { \
    half4 _B = VB(MEU, _ks); \
    half4 _A0 = TDA(I, 0*3+_ks); \
    half4 _A1 = TDA(I, 1*3+_ks); \
    half4 _A2 = TDA(I, 2*3+_ks); \
    T0 = MFMA16(_A0, _B, T0, 0, 0, 0); \
    T1 = MFMA16(_A1, _B, T1, 0, 0, 0); \
    T2 = MFMA16(_A2, _B, T2, 0, 0, 0); \
  } \
} while(0)

// err/me for 2 comps: 1 pkrtz + 1 pk_ashr + not + 2 and + 1 pk_sub
#define PREP2(PLO, PHI, VU32, ERRU, MEU) do { \
  uint32_t _p = B32H(PKRTZ((PLO), (PHI))); \
  uint32_t _sm = __builtin_bit_cast(uint32_t, \
      (short2v)(__builtin_bit_cast(short2v, _p) >> 15)); \
  uint32_t _nsm = ~_sm; \
  uint32_t _rl = _p & _nsm; \
  h2 _e = H2U(VU32) - H2U(_rl); \
  ERRU = B32H(_e); \
  MEU = ERRU & _nsm; \
} while(0)

// update 2 comps: 1 pkrtz + pk_sub + pk_mul/fma + pk_max + pk_min
#define UPD2(TLO, THI, EPKU, VU, ERRU) do { \
  uint32_t _t = B32H(PKRTZ((TLO), (THI))); \
  h2 _d = H2U(EPKU) - H2U(_t); \
  h2 _nv = H2U(VU) - HLR2*_d; \
  _nv = __builtin_elementwise_min(__builtin_elementwise_max(_nv, NCLP2), PCLP2); \
  VU = B32H(_nv); \
  EPKU = ERRU; \
} while(0)

#define LAYER_STEP(I) do { \
  f32x4 _p0, _p1, _p2; \
  PRED48(vhu[(I)-1], ((I)-1)*4608, (I)-1, _p0, _p1, _p2); \
  uint32_t _err[6], _me[6]; \
  PREP2(_p0[0], _p0[1], vhu[I][0], _err[0], _me[0]); \
  PREP2(_p0[2], _p0[3], vhu[I][1], _err[1], _me[1]); \
  PREP2(_p1[0], _p1[1], vhu[I][2], _err[2], _me[2]); \
  PREP2(_p1[2], _p1[3], vhu[I][3], _err[3], _me[3]); \
  PREP2(_p2[0], _p2[1], vhu[I][4], _err[4], _me[4]); \
  PREP2(_p2[2], _p2[3], vhu[I][5], _err[5], _me[5]); \
  f32x4 _t0, _t1, _t2; \
  TD48(_me, I, _t0, _t1, _t2); \
  UPD2(_t0[0], _t0[1], epku[0], vhu[(I)-1][0], _err[0]); \
  UPD2(_t0[2], _t0[3], epku[1], vhu[(I)-1][1], _err[1]); \
  UPD2(_t1[0], _t1[1], epku[2], vhu[(I)-1][2], _err[2]); \
  UPD2(_t1[2], _t1[3], epku[3], vhu[(I)-1][3], _err[3]); \
  UPD2(_t2[0], _t2[1], epku[4], vhu[(I)-1][4], _err[4]); \
  UPD2(_t2[2], _t2[3], epku[5], vhu[(I)-1][5], _err[5]); \
} while(0)

#define FWD(I) do { \
  f32x4 _p0, _p1, _p2; \
  PRED48(vhu[(I)-1], ((I)-1)*4608, (I)-1, _p0, _p1, _p2); \
  vhu[I][0] = PACKU(fmaxf(_p0[0],0.f), fmaxf(_p0[1],0.f)); \
  vhu[I][1] = PACKU(fmaxf(_p0[2],0.f), fmaxf(_p0[3],0.f)); \
  vhu[I][2] = PACKU(fmaxf(_p1[0],0.f), fmaxf(_p1[1],0.f)); \
  vhu[I][3] = PACKU(fmaxf(_p1[2],0.f), fmaxf(_p1[3],0.f)); \
  vhu[I][4] = PACKU(fmaxf(_p2[0],0.f), fmaxf(_p2[1],0.f)); \
  vhu[I][5] = PACKU(fmaxf(_p2[2],0.f), fmaxf(_p2[3],0.f)); \
} while(0)

__global__ __launch_bounds__(BLOCK)
void pcnet_kernel(const float* __restrict__ x, const int* __restrict__ target,
                  const float* __restrict__ W0, const float* __restrict__ b0,
                  const float* __restrict__ Wh, const float* __restrict__ bh,
                  const float* __restrict__ Wout, const float* __restrict__ bout,
                  float* __restrict__ out)
{
    const int t = threadIdx.x;
    const int lane = t & 63;
    const int wv = t >> 6;
    const int n = lane & 15;    // own sample within wave
    const int b = lane >> 4;    // comp sub-block 0..3 (owns comps 16t+4b+q)

    const int bsamp0 = blockIdx.x*256 + wv*16;   // wave's first sample (16 waves)
    const int samp = bsamp0 + n;

    const h2 HLR2  = (h2)(_Float16)0.1f;
    const h2 PCLP2 = (h2)(_Float16)10.0f;
    const h2 NCLP2 = (h2)(_Float16)(-10.0f);

    // ======== phase 0: a0 = relu(x@W0^T + b0) via MFMA; x is B-operand ========
    f32x4 acc0[3];
    #pragma unroll
    for (int tm = 0; tm < 3; ++tm) acc0[tm] = (f32x4){0.f, 0.f, 0.f, 0.f};

    const float* xrow = x + (size_t)samp*784;
    for (int ch = 0; ch < 7; ++ch) {
        __syncthreads();
        for (int idx = t; idx < 1344; idx += BLOCK) {
            int st = idx >> 6, LB = idx & 63;
            int tm = st / 7, ksl = st - tm*7;
            int row = 16*tm + (LB & 15);
            int col = ch*112 + ksl*16 + 4*(LB >> 4);
            float4 w4 = *(const float4*)(W0 + row*784 + col);
            *(half4*)(smem + (tm*7+ksl)*512 + LB*8) = PACK4(w4.x, w4.y, w4.z, w4.w);
        }
        __syncthreads();
        #pragma unroll
        for (int ksl = 0; ksl < 7; ++ksl) {
            float4 xv = *(const float4*)(xrow + ch*112 + ksl*16 + 4*b);
            half4 xb = PACK4(xv.x, xv.y, xv.z, xv.w);
            #pragma unroll
            for (int tm = 0; tm < 3; ++tm) {
                half4 A = *(const half4*)(smem + (tm*7+ksl)*512 + lane*8);
                acc0[tm] = MFMA16(A, xb, acc0[tm], 0, 0, 0);
            }
        }
    }

    uint32_t vhu[10][6], a0u[6];
    #pragma unroll
    for (int tm = 0; tm < 3; ++tm) {
        float4 bb = *(const float4*)(b0 + 16*tm + 4*b);
        uint32_t lo = PACKU(fmaxf(acc0[tm][0] + bb.x, 0.f), fmaxf(acc0[tm][1] + bb.y, 0.f));
        uint32_t hi = PACKU(fmaxf(acc0[tm][2] + bb.z, 0.f), fmaxf(acc0[tm][3] + bb.w, 0.f));
        a0u[2*tm] = lo;   vhu[0][2*tm] = lo;
        a0u[2*tm+1] = hi; vhu[0][2*tm+1] = hi;
    }
    __syncthreads();   // phase-0 reads done before WH staging overwrites

    // ======== stage pred A-frags: 9 layers x 9 subtiles (f16, 8B/lane) ========
    for (int idx = t; idx < 5184; idx += BLOCK) {
        int L = idx / 576;
        int r2 = idx - L*576;
        int st = r2 >> 6, LB = r2 & 63;
        int tm = st / 3, ks = st - tm*3;
        int m  = 16*tm + (LB & 15);
        int k0 = 16*ks + 4*(LB >> 4);
        float4 w4 = *(const float4*)(Wh + L*2304 + m*48 + k0);
        *(half4*)(smem + L*4608 + st*512 + LB*8) = PACK4(w4.x, w4.y, w4.z, w4.w);
    }
    // ======== stage td A-frags: layers I=6..9 (Wh layer 5..8), transposed ======
    for (int idx = t; idx < 2304; idx += BLOCK) {
        int Lt = idx / 576;
        int r2 = idx - Lt*576;
        int st = r2 >> 6, LB = r2 & 63;
        int tm = st / 3, ks = st - tm*3;
        int m  = 16*tm + (LB & 15);
        int k0 = 16*ks + 4*(LB >> 4);
        const float* p = Wh + (Lt+5)*2304 + k0*48 + m;
        *(half4*)(smem + TD_OFF + Lt*4608 + st*512 + LB*8) = PACK4(p[0], p[48], p[96], p[144]);
    }
    for (int idx = t; idx < 432; idx += BLOCK)
        *(float*)(smem + BH_OFF + idx*4) = bh[idx];
    __syncthreads();   // last barrier -- settling loop is barrier-free

    // ======== hoist td frags (layers 1-5), output-layer frags, bias ========
    half4 tdreg[5][9];
    #pragma unroll
    for (int L = 0; L < 5; ++L)
        #pragma unroll
        for (int st = 0; st < 9; ++st) {
            int tm = st / 3, ks = st - tm*3;
            int m  = 16*tm + (lane & 15);
            int k0 = 16*ks + 4*(lane >> 4);
            const float* p = Wh + L*2304 + k0*48 + m;
            tdreg[L][st] = PACK4(p[0], p[48], p[96], p[144]);
        }
    half4 WP[3], WT[3];
    {
        int c = lane & 15;
        #pragma unroll
        for (int ks = 0; ks < 3; ++ks) {
            if (c < 10) {
                float4 w4 = *(const float4*)(Wout + c*48 + 16*ks + 4*(lane >> 4));
                WP[ks] = PACK4(w4.x, w4.y, w4.z, w4.w);
            } else {
                WP[ks] = PACK4(0.f, 0.f, 0.f, 0.f);
            }
        }
        int c0 = 4*(lane >> 4);
        #pragma unroll
        for (int tm = 0; tm < 3; ++tm) {
            int m = 16*tm + (lane & 15);
            float w0 = (c0+0 < 10) ? Wout[(c0+0)*48 + m] : 0.f;
            float w1 = (c0+1 < 10) ? Wout[(c0+1)*48 + m] : 0.f;
            float w2 = (c0+2 < 10) ? Wout[(c0+2)*48 + m] : 0.f;
            float w3 = (c0+3 < 10) ? Wout[(c0+3)*48 + m] : 0.f;
            WT[tm] = PACK4(w0, w1, w2, w3);
        }
    }
    f32x4 bo4;
    #pragma unroll
    for (int q = 0; q < 4; ++q) bo4[q] = (4*b+q < 10) ? bout[4*b+q] : 0.f;
    const int tg = target[samp];

    // ======== forward init layers 1..9 ========
    FWD(1); FWD(2); FWD(3); FWD(4); FWD(5); FWD(6); FWD(7); FWD(8); FWD(9);
    SCHEDB(0);

    // ======== settling ========
    #pragma unroll 1
    for (int s = 0; s < 20; ++s) {
        uint32_t epku[6];
        #pragma unroll
        for (int j = 0; j < 6; ++j)
            epku[j] = B32H(H2U(vhu[0][j]) - H2U(a0u[j]));

        LAYER_STEP(1); LAYER_STEP(2); LAYER_STEP(3);
        SCHEDB(0);
        LAYER_STEP(4); LAYER_STEP(5); LAYER_STEP(6);
        SCHEDB(0);
        LAYER_STEP(7); LAYER_STEP(8); LAYER_STEP(9);
        SCHEDB(0);

        // ---- output layer, fully lane-local, packed update ----
        {
            f32x4 accP = bo4;
            #pragma unroll
            for (int ks = 0; ks < 3; ++ks)
                accP = MFMA16(WP[ks], VB(vhu[9], ks), accP, 0, 0, 0);
            int c0 = 4*b;
            float e0 = (c0+0 < 10) ? (((c0+0 == tg) ? 1.f : 0.f) - accP[0]) : 0.f;
            float e1 = (c0+1 < 10) ? (((c0+1 == tg) ? 1.f : 0.f) - accP[1]) : 0.f;
            float e2 = (c0+2 < 10) ? (((c0+2 == tg) ? 1.f : 0.f) - accP[2]) : 0.f;
            float e3 = (c0+3 < 10) ? (((c0+3 == tg) ? 1.f : 0.f) - accP[3]) : 0.f;
            uint32_t eBu[2];
            eBu[0] = B32H(PKRTZ(e0, e1));
            eBu[1] = B32H(PKRTZ(e2, e3));
            half4 eB = VB(eBu, 0);
            #pragma unroll
            for (int tm = 0; tm < 3; ++tm) {
                f32x4 a2 = {0.f, 0.f, 0.f, 0.f};
                a2 = MFMA16(WT[tm], eB, a2, 0, 0, 0);
                {
                    uint32_t _t = B32H(PKRTZ(a2[0], a2[1]));
                    h2 _d = H2U(epku[2*tm]) - H2U(_t);
                    h2 _nv = H2U(vhu[9][2*tm]) - HLR2*_d;
                    _nv = __builtin_elementwise_min(__builtin_elementwise_max(_nv, NCLP2), PCLP2);
                    vhu[9][2*tm] = B32H(_nv);
                }
                {
                    uint32_t _t = B32H(PKRTZ(a2[2], a2[3]));
                    h2 _d = H2U(epku[2*tm+1]) - H2U(_t);
                    h2 _nv = H2U(vhu[9][2*tm+1]) - HLR2*_d;
                    _nv = __builtin_elementwise_min(__builtin_elementwise_max(_nv, NCLP2), PCLP2);
                    vhu[9][2*tm+1] = B32H(_nv);
                }
            }
            SCHEDB(0);
        }
    }

    // ======== write V: out[L][sample][comp] (unpack once) ========
    #pragma unroll
    for (int L2 = 0; L2 < 10; ++L2) {
        #pragma unroll
        for (int tt = 0; tt < 3; ++tt) {
            h2 lo = H2U(vhu[L2][2*tt]);
            h2 hi = H2U(vhu[L2][2*tt+1]);
            f32x4 w4 = { (float)lo[0], (float)lo[1], (float)hi[0], (float)hi[1] };
            *(f32x4*)(out + (size_t)L2*65536*48 + (size_t)samp*48 + tt*16 + 4*b) = w4;
        }
    }
}

extern "C" void kernel_launch(void* const* d_in, const int* in_sizes, int n_in,
                              void* d_out, int out_size, void* d_ws, size_t ws_size,
                              hipStream_t stream) {
    const float* x      = (const float*)d_in[0];
    const int*   target = (const int*)d_in[1];
    const float* W0     = (const float*)d_in[2];
    const float* b0     = (const float*)d_in[3];
    const float* Wh     = (const float*)d_in[4];
    const float* bh     = (const float*)d_in[5];
    const float* Wout   = (const float*)d_in[6];
    const float* bout   = (const float*)d_in[7];
    float* out = (float*)d_out;

    hipFuncSetAttribute((const void*)pcnet_kernel,
                        hipFuncAttributeMaxDynamicSharedMemorySize, LDS_BYTES);

    dim3 grid(65536/256);   // 256 blocks, 256 samples each -> 1 block per CU
    dim3 block(BLOCK);      // 16 waves x 16 samples = 4 waves/SIMD from one block
    pcnet_kernel<<<grid, block, LDS_BYTES, stream>>>(x, target, W0, b0, Wh, bh, Wout, bout, out);
}

// Round 21
// 277.392 us; speedup vs baseline: 1.8660x; 1.8660x over previous
//
#include <hip/hip_runtime.h>
#include <stdint.h>

typedef __attribute__((ext_vector_type(4))) _Float16 half4;
typedef __attribute__((ext_vector_type(2))) _Float16 h2;
typedef __attribute__((ext_vector_type(4))) float f32x4;
typedef __attribute__((ext_vector_type(2))) uint32_t uint2v;
typedef __attribute__((ext_vector_type(2))) short short2v;

#define BLOCK 512
#define MFMA16 __builtin_amdgcn_mfma_f32_16x16x16f16
#define SCHEDB __builtin_amdgcn_sched_barrier
#define PKRTZ  __builtin_amdgcn_cvt_pkrtz

// LDS byte offsets (total 61632 -> 2 blocks/CU; 8 waves/block = 2 waves/SIMD)
#define TD_OFF    41472     // td A-frags layers I=6..9: 4 x 4608
#define BH_OFF    59904     // bh f32 9*48 = 1728
#define LDS_BYTES 61632

extern __shared__ unsigned char smem[];

#define B32H(X) __builtin_bit_cast(uint32_t, (X))
#define H2U(X)  __builtin_bit_cast(h2, (X))

// RNE pack (scalar casts; off hot path)
#define PACK4(S0,S1,S2,S3) __extension__({ \
  half4 _b; \
  _b[0] = (_Float16)(S0); _b[1] = (_Float16)(S1); \
  _b[2] = (_Float16)(S2); _b[3] = (_Float16)(S3); \
  _b; })
#define PACKU(S0,S1) __extension__({ \
  h2 _x; _x[0] = (_Float16)(S0); _x[1] = (_Float16)(S1); B32H(_x); })

// build half4 MFMA operand from two u32 state words (compile-time indices)
#define VB(ROW, KS) __extension__({ \
  uint2v _u; _u[0] = (ROW)[2*(KS)]; _u[1] = (ROW)[2*(KS)+1]; \
  __builtin_bit_cast(half4, _u); })

// td A-frag selector: layers 1-5 from registers, 6-9 from LDS (I literal)
#define TDA(I, ST) ((I) <= 5 \
  ? tdreg[(I) <= 5 ? (I)-1 : 0][ST] \
  : *(const half4*)(smem + TD_OFF + ((I) >= 6 ? (I)-6 : 0)*4608 + (ST)*512 + lane*8))

// pred 48x48 matvec; B = packed f16 state words directly; bias C-init from bh LDS.
#define PRED48(SRCU, WOFF, LIDX, P0, P1, P2) do { \
  P0 = *(const f32x4*)(smem + BH_OFF + ((LIDX)*48 +  0)*4 + b*16); \
  P1 = *(const f32x4*)(smem + BH_OFF + ((LIDX)*48 + 16)*4 + b*16); \
  P2 = *(const f32x4*)(smem + BH_OFF + ((LIDX)*48 + 32)*4 + b*16); \
  _Pragma("unroll") \
  for (int _ks = 0; _ks < 3; ++_ks) { \
    half4 _B = VB(SRCU, _ks); \
    half4 _A0 = *(const half4*)(smem + (WOFF) + (0*3+_ks)*512 + lane*8); \
    half4 _A1 = *(const half4*)(smem + (WOFF) + (1*3+_ks)*512 + lane*8); \
    half4 _A2 = *(const half4*)(smem + (WOFF) + (2*3+_ks)*512 + lane*8); \
    P0 = MFMA16(_A0, _B, P0, 0, 0, 0); \
    P1 = MFMA16(_A1, _B, P1, 0, 0, 0); \
    P2 = MFMA16(_A2, _B, P2, 0, 0, 0); \
  } \
} while(0)

// td 48x48 matvec; B = packed me words. I literal.
#define TD48(MEU, I, T0, T1, T2) do { \
  T0 = (f32x4){0.f,0.f,0.f,0.f}; T1 = T0; T2 = T0; \
  _Pragma("unroll") \
  for (int _ks = 0; _ks < 3; ++_ks) { \
    half4 _B = VB(MEU, _ks); \
    half4 _A0 = TDA(I, 0*3+_ks); \
    half4 _A1 = TDA(I, 1*3+_ks); \
    half4 _A2 = TDA(I, 2*3+_ks); \
    T0 = MFMA16(_A0, _B, T0, 0, 0, 0); \
    T1 = MFMA16(_A1, _B, T1, 0, 0, 0); \
    T2 = MFMA16(_A2, _B, T2, 0, 0, 0); \
  } \
} while(0)

// err/me for 2 comps (5 VALU after pkrtz): relu via pk_max; mask only for me.
#define PREP2(PLO, PHI, VU32, ERRU, MEU) do { \
  uint32_t _p = B32H(PKRTZ((PLO), (PHI))); \
  uint32_t _sm = __builtin_bit_cast(uint32_t, \
      (short2v)(__builtin_bit_cast(short2v, _p) >> 15)); \
  h2 _rl = __builtin_elementwise_max(H2U(_p), ZH2); \
  h2 _e = H2U(VU32) - _rl; \
  ERRU = B32H(_e); \
  MEU = ERRU & ~_sm; \
} while(0)

// update 2 comps: 1 pkrtz + pk_sub + pk_fma + pk_max + pk_min
#define UPD2(TLO, THI, EPKU, VU, ERRU) do { \
  uint32_t _t = B32H(PKRTZ((TLO), (THI))); \
  h2 _d = H2U(EPKU) - H2U(_t); \
  h2 _nv = H2U(VU) - HLR2*_d; \
  _nv = __builtin_elementwise_min(__builtin_elementwise_max(_nv, NCLP2), PCLP2); \
  VU = B32H(_nv); \
  EPKU = ERRU; \
} while(0)

#define LAYER_STEP(I) do { \
  f32x4 _p0, _p1, _p2; \
  PRED48(vhu[(I)-1], ((I)-1)*4608, (I)-1, _p0, _p1, _p2); \
  uint32_t _err[6], _me[6]; \
  PREP2(_p0[0], _p0[1], vhu[I][0], _err[0], _me[0]); \
  PREP2(_p0[2], _p0[3], vhu[I][1], _err[1], _me[1]); \
  PREP2(_p1[0], _p1[1], vhu[I][2], _err[2], _me[2]); \
  PREP2(_p1[2], _p1[3], vhu[I][3], _err[3], _me[3]); \
  PREP2(_p2[0], _p2[1], vhu[I][4], _err[4], _me[4]); \
  PREP2(_p2[2], _p2[3], vhu[I][5], _err[5], _me[5]); \
  f32x4 _t0, _t1, _t2; \
  TD48(_me, I, _t0, _t1, _t2); \
  UPD2(_t0[0], _t0[1], epku[0], vhu[(I)-1][0], _err[0]); \
  UPD2(_t0[2], _t0[3], epku[1], vhu[(I)-1][1], _err[1]); \
  UPD2(_t1[0], _t1[1], epku[2], vhu[(I)-1][2], _err[2]); \
  UPD2(_t1[2], _t1[3], epku[3], vhu[(I)-1][3], _err[3]); \
  UPD2(_t2[0], _t2[1], epku[4], vhu[(I)-1][4], _err[4]); \
  UPD2(_t2[2], _t2[3], epku[5], vhu[(I)-1][5], _err[5]); \
} while(0)

#define FWD(I) do { \
  f32x4 _p0, _p1, _p2; \
  PRED48(vhu[(I)-1], ((I)-1)*4608, (I)-1, _p0, _p1, _p2); \
  vhu[I][0] = PACKU(fmaxf(_p0[0],0.f), fmaxf(_p0[1],0.f)); \
  vhu[I][1] = PACKU(fmaxf(_p0[2],0.f), fmaxf(_p0[3],0.f)); \
  vhu[I][2] = PACKU(fmaxf(_p1[0],0.f), fmaxf(_p1[1],0.f)); \
  vhu[I][3] = PACKU(fmaxf(_p1[2],0.f), fmaxf(_p1[3],0.f)); \
  vhu[I][4] = PACKU(fmaxf(_p2[0],0.f), fmaxf(_p2[1],0.f)); \
  vhu[I][5] = PACKU(fmaxf(_p2[2],0.f), fmaxf(_p2[3],0.f)); \
} while(0)

__global__ __launch_bounds__(BLOCK)
void pcnet_kernel(const float* __restrict__ x, const int* __restrict__ target,
                  const float* __restrict__ W0, const float* __restrict__ b0,
                  const float* __restrict__ Wh, const float* __restrict__ bh,
                  const float* __restrict__ Wout, const float* __restrict__ bout,
                  float* __restrict__ out)
{
    const int t = threadIdx.x;
    const int lane = t & 63;
    const int wv = t >> 6;
    const int n = lane & 15;    // own sample within wave
    const int b = lane >> 4;    // comp sub-block 0..3 (owns comps 16t+4b+q)

    const int bsamp0 = blockIdx.x*128 + wv*16;   // wave's first sample (8 waves)
    const int samp = bsamp0 + n;

    const h2 HLR2  = (h2)(_Float16)0.1f;
    const h2 PCLP2 = (h2)(_Float16)10.0f;
    const h2 NCLP2 = (h2)(_Float16)(-10.0f);
    const h2 ZH2   = (h2)(_Float16)0.0f;

    // ======== phase 0: a0 = relu(x@W0^T + b0) via MFMA; x is B-operand ========
    f32x4 acc0[3];
    #pragma unroll
    for (int tm = 0; tm < 3; ++tm) acc0[tm] = (f32x4){0.f, 0.f, 0.f, 0.f};

    const float* xrow = x + (size_t)samp*784;
    for (int ch = 0; ch < 7; ++ch) {
        __syncthreads();
        for (int idx = t; idx < 1344; idx += BLOCK) {
            int st = idx >> 6, LB = idx & 63;
            int tm = st / 7, ksl = st - tm*7;
            int row = 16*tm + (LB & 15);
            int col = ch*112 + ksl*16 + 4*(LB >> 4);
            float4 w4 = *(const float4*)(W0 + row*784 + col);
            *(half4*)(smem + (tm*7+ksl)*512 + LB*8) = PACK4(w4.x, w4.y, w4.z, w4.w);
        }
        __syncthreads();
        #pragma unroll
        for (int ksl = 0; ksl < 7; ++ksl) {
            float4 xv = *(const float4*)(xrow + ch*112 + ksl*16 + 4*b);
            half4 xb = PACK4(xv.x, xv.y, xv.z, xv.w);
            #pragma unroll
            for (int tm = 0; tm < 3; ++tm) {
                half4 A = *(const half4*)(smem + (tm*7+ksl)*512 + lane*8);
                acc0[tm] = MFMA16(A, xb, acc0[tm], 0, 0, 0);
            }
        }
    }

    uint32_t vhu[10][6], a0u[6];
    #pragma unroll
    for (int tm = 0; tm < 3; ++tm) {
        float4 bb = *(const float4*)(b0 + 16*tm + 4*b);
        uint32_t lo = PACKU(fmaxf(acc0[tm][0] + bb.x, 0.f), fmaxf(acc0[tm][1] + bb.y, 0.f));
        uint32_t hi = PACKU(fmaxf(acc0[tm][2] + bb.z, 0.f), fmaxf(acc0[tm][3] + bb.w, 0.f));
        a0u[2*tm] = lo;   vhu[0][2*tm] = lo;
        a0u[2*tm+1] = hi; vhu[0][2*tm+1] = hi;
    }
    __syncthreads();   // phase-0 reads done before WH staging overwrites

    // ======== stage pred A-frags: 9 layers x 9 subtiles (f16, 8B/lane) ========
    for (int idx = t; idx < 5184; idx += BLOCK) {
        int L = idx / 576;
        int r2 = idx - L*576;
        int st = r2 >> 6, LB = r2 & 63;
        int tm = st / 3, ks = st - tm*3;
        int m  = 16*tm + (LB & 15);
        int k0 = 16*ks + 4*(LB >> 4);
        float4 w4 = *(const float4*)(Wh + L*2304 + m*48 + k0);
        *(half4*)(smem + L*4608 + st*512 + LB*8) = PACK4(w4.x, w4.y, w4.z, w4.w);
    }
    // ======== stage td A-frags: layers I=6..9 (Wh layer 5..8), transposed ======
    for (int idx = t; idx < 2304; idx += BLOCK) {
        int Lt = idx / 576;
        int r2 = idx - Lt*576;
        int st = r2 >> 6, LB = r2 & 63;
        int tm = st / 3, ks = st - tm*3;
        int m  = 16*tm + (LB & 15);
        int k0 = 16*ks + 4*(LB >> 4);
        const float* p = Wh + (Lt+5)*2304 + k0*48 + m;
        *(half4*)(smem + TD_OFF + Lt*4608 + st*512 + LB*8) = PACK4(p[0], p[48], p[96], p[144]);
    }
    for (int idx = t; idx < 432; idx += BLOCK)
        *(float*)(smem + BH_OFF + idx*4) = bh[idx];
    __syncthreads();   // last barrier -- settling loop is barrier-free

    // ======== hoist td frags (layers 1-5), output-layer frags, bias ========
    half4 tdreg[5][9];
    #pragma unroll
    for (int L = 0; L < 5; ++L)
        #pragma unroll
        for (int st = 0; st < 9; ++st) {
            int tm = st / 3, ks = st - tm*3;
            int m  = 16*tm + (lane & 15);
            int k0 = 16*ks + 4*(lane >> 4);
            const float* p = Wh + L*2304 + k0*48 + m;
            tdreg[L][st] = PACK4(p[0], p[48], p[96], p[144]);
        }
    half4 WP[3], WT[3];
    {
        int c = lane & 15;
        #pragma unroll
        for (int ks = 0; ks < 3; ++ks) {
            if (c < 10) {
                float4 w4 = *(const float4*)(Wout + c*48 + 16*ks + 4*(lane >> 4));
                WP[ks] = PACK4(w4.x, w4.y, w4.z, w4.w);
            } else {
                WP[ks] = PACK4(0.f, 0.f, 0.f, 0.f);
            }
        }
        int c0 = 4*(lane >> 4);
        #pragma unroll
        for (int tm = 0; tm < 3; ++tm) {
            int m = 16*tm + (lane & 15);
            float w0 = (c0+0 < 10) ? Wout[(c0+0)*48 + m] : 0.f;
            float w1 = (c0+1 < 10) ? Wout[(c0+1)*48 + m] : 0.f;
            float w2 = (c0+2 < 10) ? Wout[(c0+2)*48 + m] : 0.f;
            float w3 = (c0+3 < 10) ? Wout[(c0+3)*48 + m] : 0.f;
            WT[tm] = PACK4(w0, w1, w2, w3);
        }
    }
    f32x4 bo4;
    #pragma unroll
    for (int q = 0; q < 4; ++q) bo4[q] = (4*b+q < 10) ? bout[4*b+q] : 0.f;
    const int tg = target[samp];

    // ======== forward init layers 1..9 ========
    FWD(1); FWD(2); FWD(3); FWD(4); FWD(5); FWD(6); FWD(7); FWD(8); FWD(9);
    SCHEDB(0);

    // ======== settling ========
    #pragma unroll 1
    for (int s = 0; s < 20; ++s) {
        uint32_t epku[6];
        #pragma unroll
        for (int j = 0; j < 6; ++j)
            epku[j] = B32H(H2U(vhu[0][j]) - H2U(a0u[j]));

        LAYER_STEP(1); LAYER_STEP(2); LAYER_STEP(3);
        SCHEDB(0);
        LAYER_STEP(4); LAYER_STEP(5); LAYER_STEP(6);
        SCHEDB(0);
        LAYER_STEP(7); LAYER_STEP(8); LAYER_STEP(9);
        SCHEDB(0);

        // ---- output layer, fully lane-local, packed update ----
        {
            f32x4 accP = bo4;
            #pragma unroll
            for (int ks = 0; ks < 3; ++ks)
                accP = MFMA16(WP[ks], VB(vhu[9], ks), accP, 0, 0, 0);
            int c0 = 4*b;
            float e0 = (c0+0 < 10) ? (((c0+0 == tg) ? 1.f : 0.f) - accP[0]) : 0.f;
            float e1 = (c0+1 < 10) ? (((c0+1 == tg) ? 1.f : 0.f) - accP[1]) : 0.f;
            float e2 = (c0+2 < 10) ? (((c0+2 == tg) ? 1.f : 0.f) - accP[2]) : 0.f;
            float e3 = (c0+3 < 10) ? (((c0+3 == tg) ? 1.f : 0.f) - accP[3]) : 0.f;
            uint32_t eBu[2];
            eBu[0] = B32H(PKRTZ(e0, e1));
            eBu[1] = B32H(PKRTZ(e2, e3));
            half4 eB = VB(eBu, 0);
            #pragma unroll
            for (int tm = 0; tm < 3; ++tm) {
                f32x4 a2 = {0.f, 0.f, 0.f, 0.f};
                a2 = MFMA16(WT[tm], eB, a2, 0, 0, 0);
                {
                    uint32_t _t = B32H(PKRTZ(a2[0], a2[1]));
                    h2 _d = H2U(epku[2*tm]) - H2U(_t);
                    h2 _nv = H2U(vhu[9][2*tm]) - HLR2*_d;
                    _nv = __builtin_elementwise_min(__builtin_elementwise_max(_nv, NCLP2), PCLP2);
                    vhu[9][2*tm] = B32H(_nv);
                }
                {
                    uint32_t _t = B32H(PKRTZ(a2[2], a2[3]));
                    h2 _d = H2U(epku[2*tm+1]) - H2U(_t);
                    h2 _nv = H2U(vhu[9][2*tm+1]) - HLR2*_d;
                    _nv = __builtin_elementwise_min(__builtin_elementwise_max(_nv, NCLP2), PCLP2);
                    vhu[9][2*tm+1] = B32H(_nv);
                }
            }
            SCHEDB(0);
        }
    }

    // ======== write V: out[L][sample][comp] (unpack once) ========
    #pragma unroll
    for (int L2 = 0; L2 < 10; ++L2) {
        #pragma unroll
        for (int tt = 0; tt < 3; ++tt) {
            h2 lo = H2U(vhu[L2][2*tt]);
            h2 hi = H2U(vhu[L2][2*tt+1]);
            f32x4 w4 = { (float)lo[0], (float)lo[1], (float)hi[0], (float)hi[1] };
            *(f32x4*)(out + (size_t)L2*65536*48 + (size_t)samp*48 + tt*16 + 4*b) = w4;
        }
    }
}

extern "C" void kernel_launch(void* const* d_in, const int* in_sizes, int n_in,
                              void* d_out, int out_size, void* d_ws, size_t ws_size,
                              hipStream_t stream) {
    const float* x      = (const float*)d_in[0];
    const int*   target = (const int*)d_in[1];
    const float* W0     = (const float*)d_in[2];
    const float* b0     = (const float*)d_in[3];
    const float* Wh     = (const float*)d_in[4];
    const float* bh     = (const float*)d_in[5];
    const float* Wout   = (const float*)d_in[6];
    const float* bout   = (const float*)d_in[7];
    float* out = (float*)d_out;

    hipFuncSetAttribute((const void*)pcnet_kernel,
                        hipFuncAttributeMaxDynamicSharedMemorySize, LDS_BYTES);

    dim3 grid(65536/128);   // 512 blocks, 128 samples each
    dim3 block(BLOCK);      // 8 waves x 16 samples; 61632 B LDS -> 2 blocks/CU
    pcnet_kernel<<<grid, block, LDS_BYTES, stream>>>(x, target, W0, b0, Wh, bh, Wout, bout, out);
}

// Round 22
// 268.296 us; speedup vs baseline: 1.9292x; 1.0339x over previous
//
#include <hip/hip_runtime.h>
#include <stdint.h>

typedef __attribute__((ext_vector_type(4))) _Float16 half4;
typedef __attribute__((ext_vector_type(8))) _Float16 half8;
typedef __attribute__((ext_vector_type(2))) _Float16 h2;
typedef __attribute__((ext_vector_type(4))) float f32x4;
typedef __attribute__((ext_vector_type(2))) uint32_t uint2v;
typedef __attribute__((ext_vector_type(4))) uint32_t uint4v;
typedef __attribute__((ext_vector_type(2))) short short2v;

#define BLOCK 512
#define MFMA16 __builtin_amdgcn_mfma_f32_16x16x16f16
#define MFMA32 __builtin_amdgcn_mfma_f32_16x16x32_f16
#define SCHEDB __builtin_amdgcn_sched_barrier
#define PKRTZ  __builtin_amdgcn_cvt_pkrtz

// LDS: pred frags 9x6144 | td frags 9x6144 | bh  (512-thr -> 1 block/CU anyway)
#define PRED_OFF  0
#define TD_OFF    55296
#define BH_OFF    110592
#define LDS_BYTES 112320

extern __shared__ unsigned char smem[];

#define B32H(X) __builtin_bit_cast(uint32_t, (X))
#define H2U(X)  __builtin_bit_cast(h2, (X))

#define PACK4(S0,S1,S2,S3) __extension__({ \
  half4 _b; \
  _b[0] = (_Float16)(S0); _b[1] = (_Float16)(S1); \
  _b[2] = (_Float16)(S2); _b[3] = (_Float16)(S3); \
  _b; })
#define PACKU(S0,S1) __extension__({ \
  h2 _x; _x[0] = (_Float16)(S0); _x[1] = (_Float16)(S1); B32H(_x); })

// half4 operand from two state words (legacy K=16 output layer)
#define VB(ROW, KS) __extension__({ \
  uint2v _u; _u[0] = (ROW)[2*(KS)]; _u[1] = (ROW)[2*(KS)+1]; \
  __builtin_bit_cast(half4, _u); })

// half8 B-frag for K=32 call ks: state words 3ks..3ks+2 + zero pad (j=6,7)
#define BFRAG(SRCU, KS) __extension__({ \
  uint4v _u; _u[0] = (SRCU)[3*(KS)]; _u[1] = (SRCU)[3*(KS)+1]; \
  _u[2] = (SRCU)[3*(KS)+2]; _u[3] = 0u; \
  __builtin_bit_cast(half8, _u); })

// pred 48x48 matvec via mfma 16x16x32 (K=64, pads zeroed both sides)
#define PRED48(SRCU, LAY, P0, P1, P2) do { \
  const unsigned char* _wb = smem + PRED_OFF + (LAY)*6144; \
  P0 = *(const f32x4*)(smem + BH_OFF + ((LAY)*48 + 12*b + 0)*4); \
  P1 = *(const f32x4*)(smem + BH_OFF + ((LAY)*48 + 12*b + 4)*4); \
  P2 = *(const f32x4*)(smem + BH_OFF + ((LAY)*48 + 12*b + 8)*4); \
  _Pragma("unroll") \
  for (int _ks = 0; _ks < 2; ++_ks) { \
    half8 _B = BFRAG(SRCU, _ks); \
    half8 _A0 = *(const half8*)(_wb + (0*2+_ks)*1024 + lane*16); \
    half8 _A1 = *(const half8*)(_wb + (1*2+_ks)*1024 + lane*16); \
    half8 _A2 = *(const half8*)(_wb + (2*2+_ks)*1024 + lane*16); \
    P0 = MFMA32(_A0, _B, P0, 0, 0, 0); \
    P1 = MFMA32(_A1, _B, P1, 0, 0, 0); \
    P2 = MFMA32(_A2, _B, P2, 0, 0, 0); \
  } \
} while(0)

// td 48x48 matvec via mfma 16x16x32
#define TD48(MEU, LAY, T0, T1, T2) do { \
  const unsigned char* _wb = smem + TD_OFF + (LAY)*6144; \
  T0 = (f32x4){0.f,0.f,0.f,0.f}; T1 = T0; T2 = T0; \
  _Pragma("unroll") \
  for (int _ks = 0; _ks < 2; ++_ks) { \
    half8 _B = BFRAG(MEU, _ks); \
    half8 _A0 = *(const half8*)(_wb + (0*2+_ks)*1024 + lane*16); \
    half8 _A1 = *(const half8*)(_wb + (1*2+_ks)*1024 + lane*16); \
    half8 _A2 = *(const half8*)(_wb + (2*2+_ks)*1024 + lane*16); \
    T0 = MFMA32(_A0, _B, T0, 0, 0, 0); \
    T1 = MFMA32(_A1, _B, T1, 0, 0, 0); \
    T2 = MFMA32(_A2, _B, T2, 0, 0, 0); \
  } \
} while(0)

// err/me for 2 comps
#define PREP2(PLO, PHI, VU32, ERRU, MEU) do { \
  uint32_t _p = B32H(PKRTZ((PLO), (PHI))); \
  uint32_t _sm = __builtin_bit_cast(uint32_t, \
      (short2v)(__builtin_bit_cast(short2v, _p) >> 15)); \
  h2 _rl = __builtin_elementwise_max(H2U(_p), ZH2); \
  h2 _e = H2U(VU32) - _rl; \
  ERRU = B32H(_e); \
  MEU = ERRU & ~_sm; \
} while(0)

// packed update for 2 comps
#define UPD2(TLO, THI, EPKU, VU, ERRU) do { \
  uint32_t _t = B32H(PKRTZ((TLO), (THI))); \
  h2 _d = H2U(EPKU) - H2U(_t); \
  h2 _nv = H2U(VU) - HLR2*_d; \
  _nv = __builtin_elementwise_min(__builtin_elementwise_max(_nv, NCLP2), PCLP2); \
  VU = B32H(_nv); \
  EPKU = ERRU; \
} while(0)

#define LAYER_STEP(I) do { \
  f32x4 _p0, _p1, _p2; \
  PRED48(vhu[(I)-1], (I)-1, _p0, _p1, _p2); \
  uint32_t _err[6], _me[6]; \
  PREP2(_p0[0], _p0[1], vhu[I][0], _err[0], _me[0]); \
  PREP2(_p0[2], _p0[3], vhu[I][1], _err[1], _me[1]); \
  PREP2(_p1[0], _p1[1], vhu[I][2], _err[2], _me[2]); \
  PREP2(_p1[2], _p1[3], vhu[I][3], _err[3], _me[3]); \
  PREP2(_p2[0], _p2[1], vhu[I][4], _err[4], _me[4]); \
  PREP2(_p2[2], _p2[3], vhu[I][5], _err[5], _me[5]); \
  f32x4 _t0, _t1, _t2; \
  TD48(_me, (I)-1, _t0, _t1, _t2); \
  UPD2(_t0[0], _t0[1], epku[0], vhu[(I)-1][0], _err[0]); \
  UPD2(_t0[2], _t0[3], epku[1], vhu[(I)-1][1], _err[1]); \
  UPD2(_t1[0], _t1[1], epku[2], vhu[(I)-1][2], _err[2]); \
  UPD2(_t1[2], _t1[3], epku[3], vhu[(I)-1][3], _err[3]); \
  UPD2(_t2[0], _t2[1], epku[4], vhu[(I)-1][4], _err[4]); \
  UPD2(_t2[2], _t2[3], epku[5], vhu[(I)-1][5], _err[5]); \
} while(0)

#define FWD(I) do { \
  f32x4 _p0, _p1, _p2; \
  PRED48(vhu[(I)-1], (I)-1, _p0, _p1, _p2); \
  vhu[I][0] = PACKU(fmaxf(_p0[0],0.f), fmaxf(_p0[1],0.f)); \
  vhu[I][1] = PACKU(fmaxf(_p0[2],0.f), fmaxf(_p0[3],0.f)); \
  vhu[I][2] = PACKU(fmaxf(_p1[0],0.f), fmaxf(_p1[1],0.f)); \
  vhu[I][3] = PACKU(fmaxf(_p1[2],0.f), fmaxf(_p1[3],0.f)); \
  vhu[I][4] = PACKU(fmaxf(_p2[0],0.f), fmaxf(_p2[1],0.f)); \
  vhu[I][5] = PACKU(fmaxf(_p2[2],0.f), fmaxf(_p2[3],0.f)); \
} while(0)

__global__ __launch_bounds__(BLOCK)
void pcnet_kernel(const float* __restrict__ x, const int* __restrict__ target,
                  const float* __restrict__ W0, const float* __restrict__ b0,
                  const float* __restrict__ Wh, const float* __restrict__ bh,
                  const float* __restrict__ Wout, const float* __restrict__ bout,
                  float* __restrict__ out)
{
    const int t = threadIdx.x;
    const int lane = t & 63;
    const int wv = t >> 6;
    const int n = lane & 15;    // own sample within wave
    const int b = lane >> 4;    // comp group: owns logical comps 12b..12b+11

    const int bsamp0 = blockIdx.x*128 + wv*16;
    const int samp = bsamp0 + n;

    const h2 HLR2  = (h2)(_Float16)0.1f;
    const h2 PCLP2 = (h2)(_Float16)10.0f;
    const h2 NCLP2 = (h2)(_Float16)(-10.0f);
    const h2 ZH2   = (h2)(_Float16)0.0f;

    // ======== phase 0: a0 = relu(x@W0^T + b0); legacy K=16 MFMA, new row map ====
    f32x4 acc0[3];
    #pragma unroll
    for (int tm = 0; tm < 3; ++tm) acc0[tm] = (f32x4){0.f, 0.f, 0.f, 0.f};

    const float* xrow = x + (size_t)samp*784;
    for (int ch = 0; ch < 7; ++ch) {
        __syncthreads();
        for (int idx = t; idx < 1344; idx += BLOCK) {
            int st = idx >> 6, LB = idx & 63;
            int tm = st / 7, ksl = st - tm*7;
            int r = LB & 15;
            int row = 12*(r>>2) + 4*tm + (r&3);          // logical row map
            int col = ch*112 + ksl*16 + 4*(LB >> 4);
            float4 w4 = *(const float4*)(W0 + row*784 + col);
            *(half4*)(smem + (tm*7+ksl)*512 + LB*8) = PACK4(w4.x, w4.y, w4.z, w4.w);
        }
        __syncthreads();
        #pragma unroll
        for (int ksl = 0; ksl < 7; ++ksl) {
            float4 xv = *(const float4*)(xrow + ch*112 + ksl*16 + 4*b);
            half4 xb = PACK4(xv.x, xv.y, xv.z, xv.w);
            #pragma unroll
            for (int tm = 0; tm < 3; ++tm) {
                half4 A = *(const half4*)(smem + (tm*7+ksl)*512 + lane*8);
                acc0[tm] = MFMA16(A, xb, acc0[tm], 0, 0, 0);
            }
        }
    }

    uint32_t vhu[10][6], a0u[6];
    #pragma unroll
    for (int tm = 0; tm < 3; ++tm) {
        float4 bb = *(const float4*)(b0 + 12*b + 4*tm);
        uint32_t lo = PACKU(fmaxf(acc0[tm][0] + bb.x, 0.f), fmaxf(acc0[tm][1] + bb.y, 0.f));
        uint32_t hi = PACKU(fmaxf(acc0[tm][2] + bb.z, 0.f), fmaxf(acc0[tm][3] + bb.w, 0.f));
        a0u[2*tm] = lo;   vhu[0][2*tm] = lo;
        a0u[2*tm+1] = hi; vhu[0][2*tm+1] = hi;
    }
    __syncthreads();   // phase-0 reads done before frag staging overwrites

    // ======== stage pred K=32 A-frags: 9 layers x 6 subtiles x 16B/lane ========
    for (int idx = t; idx < 3456; idx += BLOCK) {
        int L = idx / 384;
        int r2 = idx - L*384;
        int st = r2 >> 6, LB = r2 & 63;
        int tm = st >> 1, ks = st & 1;
        int r = LB & 15, g = LB >> 4;
        int row = 12*(r>>2) + 4*tm + (r&3);
        int c0 = 12*g + 6*ks;
        const float* p = Wh + L*2304 + row*48 + c0;
        uint4v w;
        w[0] = PACKU(p[0], p[1]); w[1] = PACKU(p[2], p[3]);
        w[2] = PACKU(p[4], p[5]); w[3] = 0u;
        *(uint4v*)(smem + PRED_OFF + L*6144 + st*1024 + LB*16) = w;
    }
    // ======== stage td K=32 A-frags (transposed), all 9 layers ========
    for (int idx = t; idx < 3456; idx += BLOCK) {
        int L = idx / 384;
        int r2 = idx - L*384;
        int st = r2 >> 6, LB = r2 & 63;
        int tm = st >> 1, ks = st & 1;
        int r = LB & 15, g = LB >> 4;
        int row = 12*(r>>2) + 4*tm + (r&3);
        int c0 = 12*g + 6*ks;
        const float* p = Wh + L*2304 + c0*48 + row;
        uint4v w;
        w[0] = PACKU(p[0], p[48]); w[1] = PACKU(p[96], p[144]);
        w[2] = PACKU(p[192], p[240]); w[3] = 0u;
        *(uint4v*)(smem + TD_OFF + L*6144 + st*1024 + LB*16) = w;
    }
    for (int idx = t; idx < 432; idx += BLOCK)
        *(float*)(smem + BH_OFF + idx*4) = bh[idx];
    __syncthreads();   // last barrier -- settling loop is barrier-free

    // ======== output-layer frags (legacy K=16), new comp labeling ========
    half4 WP[3], WT[3];
    {
        int c = lane & 15, g = lane >> 4;
        #pragma unroll
        for (int ks = 0; ks < 3; ++ks) {
            if (c < 10) {
                float4 w4 = *(const float4*)(Wout + c*48 + 12*g + 4*ks);
                WP[ks] = PACK4(w4.x, w4.y, w4.z, w4.w);
            } else {
                WP[ks] = PACK4(0.f, 0.f, 0.f, 0.f);
            }
        }
        int r = lane & 15;
        int c0 = 4*g;
        #pragma unroll
        for (int tm = 0; tm < 3; ++tm) {
            int m = 12*(r>>2) + 4*tm + (r&3);
            float w0 = (c0+0 < 10) ? Wout[(c0+0)*48 + m] : 0.f;
            float w1 = (c0+1 < 10) ? Wout[(c0+1)*48 + m] : 0.f;
            float w2 = (c0+2 < 10) ? Wout[(c0+2)*48 + m] : 0.f;
            float w3 = (c0+3 < 10) ? Wout[(c0+3)*48 + m] : 0.f;
            WT[tm] = PACK4(w0, w1, w2, w3);
        }
    }
    f32x4 bo4;
    #pragma unroll
    for (int q = 0; q < 4; ++q) bo4[q] = (4*b+q < 10) ? bout[4*b+q] : 0.f;
    const int tg = target[samp];

    // ======== forward init layers 1..9 ========
    FWD(1); FWD(2); FWD(3); FWD(4); FWD(5); FWD(6); FWD(7); FWD(8); FWD(9);
    SCHEDB(0);

    // ======== settling ========
    #pragma unroll 1
    for (int s = 0; s < 20; ++s) {
        uint32_t epku[6];
        #pragma unroll
        for (int j = 0; j < 6; ++j)
            epku[j] = B32H(H2U(vhu[0][j]) - H2U(a0u[j]));

        LAYER_STEP(1); LAYER_STEP(2); LAYER_STEP(3);
        SCHEDB(0);
        LAYER_STEP(4); LAYER_STEP(5); LAYER_STEP(6);
        SCHEDB(0);
        LAYER_STEP(7); LAYER_STEP(8); LAYER_STEP(9);
        SCHEDB(0);

        // ---- output layer (legacy K=16), lane-local packed update ----
        {
            f32x4 accP = bo4;
            #pragma unroll
            for (int ks = 0; ks < 3; ++ks)
                accP = MFMA16(WP[ks], VB(vhu[9], ks), accP, 0, 0, 0);
            int c0 = 4*b;
            float e0 = (c0+0 < 10) ? (((c0+0 == tg) ? 1.f : 0.f) - accP[0]) : 0.f;
            float e1 = (c0+1 < 10) ? (((c0+1 == tg) ? 1.f : 0.f) - accP[1]) : 0.f;
            float e2 = (c0+2 < 10) ? (((c0+2 == tg) ? 1.f : 0.f) - accP[2]) : 0.f;
            float e3 = (c0+3 < 10) ? (((c0+3 == tg) ? 1.f : 0.f) - accP[3]) : 0.f;
            uint32_t eBu[2];
            eBu[0] = B32H(PKRTZ(e0, e1));
            eBu[1] = B32H(PKRTZ(e2, e3));
            half4 eB = VB(eBu, 0);
            #pragma unroll
            for (int tm = 0; tm < 3; ++tm) {
                f32x4 a2 = {0.f, 0.f, 0.f, 0.f};
                a2 = MFMA16(WT[tm], eB, a2, 0, 0, 0);
                {
                    uint32_t _t = B32H(PKRTZ(a2[0], a2[1]));
                    h2 _d = H2U(epku[2*tm]) - H2U(_t);
                    h2 _nv = H2U(vhu[9][2*tm]) - HLR2*_d;
                    _nv = __builtin_elementwise_min(__builtin_elementwise_max(_nv, NCLP2), PCLP2);
                    vhu[9][2*tm] = B32H(_nv);
                }
                {
                    uint32_t _t = B32H(PKRTZ(a2[2], a2[3]));
                    h2 _d = H2U(epku[2*tm+1]) - H2U(_t);
                    h2 _nv = H2U(vhu[9][2*tm+1]) - HLR2*_d;
                    _nv = __builtin_elementwise_min(__builtin_elementwise_max(_nv, NCLP2), PCLP2);
                    vhu[9][2*tm+1] = B32H(_nv);
                }
            }
            SCHEDB(0);
        }
    }

    // ======== write V: lane b owns comps 12b..12b+11 (3x f32x4) ========
    #pragma unroll
    for (int L2 = 0; L2 < 10; ++L2) {
        #pragma unroll
        for (int tt = 0; tt < 3; ++tt) {
            h2 lo = H2U(vhu[L2][2*tt]);
            h2 hi = H2U(vhu[L2][2*tt+1]);
            f32x4 w4 = { (float)lo[0], (float)lo[1], (float)hi[0], (float)hi[1] };
            *(f32x4*)(out + (size_t)L2*65536*48 + (size_t)samp*48 + 12*b + 4*tt) = w4;
        }
    }
}

extern "C" void kernel_launch(void* const* d_in, const int* in_sizes, int n_in,
                              void* d_out, int out_size, void* d_ws, size_t ws_size,
                              hipStream_t stream) {
    const float* x      = (const float*)d_in[0];
    const int*   target = (const int*)d_in[1];
    const float* W0     = (const float*)d_in[2];
    const float* b0     = (const float*)d_in[3];
    const float* Wh     = (const float*)d_in[4];
    const float* bh     = (const float*)d_in[5];
    const float* Wout   = (const float*)d_in[6];
    const float* bout   = (const float*)d_in[7];
    float* out = (float*)d_out;

    hipFuncSetAttribute((const void*)pcnet_kernel,
                        hipFuncAttributeMaxDynamicSharedMemorySize, LDS_BYTES);

    dim3 grid(65536/128);   // 512 blocks, 128 samples each
    dim3 block(BLOCK);      // 8 waves x 16 samples
    pcnet_kernel<<<grid, block, LDS_BYTES, stream>>>(x, target, W0, b0, Wh, bh, Wout, bout, out);
}